// Round 11
// baseline (340.656 us; speedup 1.0000x reference)
//
#include <hip/hip_runtime.h>
#include <math.h>

// FlowLayer: 2 steps of manifold (S^2) graph heat flow.
// N=50000 nodes, C=16 channels, D=3, E=1.6M edges.
//
// Build: 8-way privatized histogram (1 atomic/edge, ~25G/s memory-side RMW
// ceiling - R6/R7), 3-phase scan, atomic-free fill packing (w, rcv*16) + 16
// zero sentinels. rcv premultiplied to the padded float4 row index.
//
// Flow: x stored padded [N][16] float4 (256B rows) so each edge-channel
// gather is ONE dwordx4 (16 lanes x 16B = one coalesced row). R10 lesson:
// the flow loop is VMEM-pipe bound (3 scalar q-loads re-touching the same
// lines tripled TA work); fp16 (R9) and packed-VALU (R10) moved little.
// Wave per node, lane=(k*16+c), 16 edges/wave-iter, float2-packed math.
//
// NOTE: |u|^2 MUST be computed from u's components (not 1-cs^2): near
// antipodal pairs 1-cs^2 cancels catastrophically -> rsq explodes (R5 bug).

constexpr float EPS64F = 2.2204460492503131e-16f;  // np.float64 eps
constexpr float PI_F   = 3.14159265358979323846f;
constexpr int   NREP   = 8;

typedef int   vi4 __attribute__((ext_vector_type(4)));
typedef float vf4 __attribute__((ext_vector_type(4)));
typedef float vf2 __attribute__((ext_vector_type(2)));

// ---------------- CSR build ----------------

__global__ __launch_bounds__(256) void hist_kernel(
    const vi4* __restrict__ snd4, int* __restrict__ rep,
    vi4* __restrict__ pos4, const int* __restrict__ snd,
    int* __restrict__ pos, int N, int E) {
  int tid = threadIdx.x;
  int E4 = E >> 2;
  #pragma unroll
  for (int gg = 0; gg < 4; ++gg) {
    int g = blockIdx.x * 1024 + gg * 256 + tid;
    if (g < E4) {
      int rb = (g & (NREP - 1)) * N;  // replica id: must match fill_kernel
      vi4 s = __builtin_nontemporal_load(&snd4[g]);
      vi4 p;
      p.x = atomicAdd(&rep[rb + s.x], 1);
      p.y = atomicAdd(&rep[rb + s.y], 1);
      p.z = atomicAdd(&rep[rb + s.z], 1);
      p.w = atomicAdd(&rep[rb + s.w], 1);
      __builtin_nontemporal_store(p, &pos4[g]);
    }
  }
  if (blockIdx.x == 0 && tid == 0) {  // scalar tail (E % 4) -> replica 0
    for (int e = E4 << 2; e < E; ++e) pos[e] = atomicAdd(&rep[snd[e]], 1);
  }
}

__global__ __launch_bounds__(1024) void scanA_kernel(
    int* __restrict__ rep, int* __restrict__ row_start,
    int* __restrict__ btot, int N) {
  __shared__ int wsum[16];
  int tid = threadIdx.x;
  int lane = tid & 63, wave = tid >> 6;
  int i = blockIdx.x * 1024 + tid;
  int v = 0;
  if (i < N) {
    int run = 0;
    int cpre[NREP];
    #pragma unroll
    for (int r = 0; r < NREP; ++r) {
      int t = rep[r * N + i];
      cpre[r] = run;
      run += t;
    }
    v = run;
    #pragma unroll
    for (int r = 0; r < NREP; ++r) rep[r * N + i] = cpre[r];
  }
  int incl = v;
  #pragma unroll
  for (int off = 1; off < 64; off <<= 1) {
    int t = __shfl_up(incl, off, 64);
    if (lane >= off) incl += t;
  }
  if (lane == 63) wsum[wave] = incl;
  __syncthreads();
  if (wave == 0 && lane < 16) {
    int wincl = wsum[lane];
    #pragma unroll
    for (int off = 1; off < 16; off <<= 1) {
      int t = __shfl_up(wincl, off, 64);
      if (lane >= off) wincl += t;
    }
    wsum[lane] = wincl;
  }
  __syncthreads();
  int woff = (wave > 0) ? wsum[wave - 1] : 0;
  if (i < N) row_start[i] = woff + incl - v;
  if (tid == 0) btot[blockIdx.x] = wsum[15];
}

__global__ __launch_bounds__(64) void scanB_kernel(
    const int* __restrict__ btot, int* __restrict__ boff,
    int* __restrict__ row_start, int nb, int N) {
  int lane = threadIdx.x;
  int v = (lane < nb) ? btot[lane] : 0;
  int incl = v;
  #pragma unroll
  for (int off = 1; off < 64; off <<= 1) {
    int t = __shfl_up(incl, off, 64);
    if (lane >= off) incl += t;
  }
  if (lane < nb) boff[lane] = incl - v;
  if (lane == 63) row_start[N] = incl;  // grand total
}

__global__ __launch_bounds__(1024) void scanC_kernel(
    int* __restrict__ row_start, const int* __restrict__ boff,
    int* __restrict__ rep, int N) {
  int i = blockIdx.x * 1024 + threadIdx.x;
  if (i < N) {
    int rs = row_start[i] + boff[blockIdx.x];
    row_start[i] = rs;
    #pragma unroll
    for (int r = 0; r < NREP; ++r) rep[r * N + i] += rs;
  }
}

// Atomic-free fill: packs (w, rcv*16); 16 zero sentinels past pair[E].
__global__ __launch_bounds__(256) void fill_kernel(
    const vi4* __restrict__ snd4, const vi4* __restrict__ rcv4,
    const vf4* __restrict__ ew4, const vi4* __restrict__ pos4,
    const int* __restrict__ rep, long long* __restrict__ pair,
    const int* __restrict__ snd, const int* __restrict__ rcv,
    const float* __restrict__ ew, const int* __restrict__ pos, int N, int E) {
  int tid = threadIdx.x;
  int E4 = E >> 2;
  #pragma unroll
  for (int gg = 0; gg < 2; ++gg) {
    int g = blockIdx.x * 512 + gg * 256 + tid;
    if (g < E4) {
      int rb = (g & (NREP - 1)) * N;  // must match hist_kernel
      vi4 s = __builtin_nontemporal_load(&snd4[g]);
      vi4 r = __builtin_nontemporal_load(&rcv4[g]);
      vf4 w = __builtin_nontemporal_load(&ew4[g]);
      vi4 p = __builtin_nontemporal_load(&pos4[g]);
      pair[rep[rb + s.x] + p.x] =
          (long long)(((unsigned long long)(unsigned)__float_as_int(w.x) << 32) | (unsigned)(r.x * 16));
      pair[rep[rb + s.y] + p.y] =
          (long long)(((unsigned long long)(unsigned)__float_as_int(w.y) << 32) | (unsigned)(r.y * 16));
      pair[rep[rb + s.z] + p.z] =
          (long long)(((unsigned long long)(unsigned)__float_as_int(w.z) << 32) | (unsigned)(r.z * 16));
      pair[rep[rb + s.w] + p.w] =
          (long long)(((unsigned long long)(unsigned)__float_as_int(w.w) << 32) | (unsigned)(r.w * 16));
    }
  }
  if (blockIdx.x == 0 && tid == 0) {
    for (int e = E4 << 2; e < E; ++e) {  // scalar tail -> replica 0
      pair[rep[snd[e]] + pos[e]] =
          (long long)(((unsigned long long)(unsigned)__float_as_int(ew[e]) << 32) | (unsigned)(rcv[e] * 16));
    }
    for (int z = 0; z < 16; ++z) pair[(size_t)E + z] = 0;  // sentinels (w=0)
  }
}

// ---------------- layout conversion ----------------

// nodes [N][48] -> xp [N*16] float4 (pad 4th comp). t = n*16+c.
__global__ __launch_bounds__(256) void conv_kernel(
    const float* __restrict__ xf, vf4* __restrict__ xp, int NC) {
  int t = blockIdx.x * 256 + threadIdx.x;
  if (t >= NC) return;
  vf4 v;
  v.x = xf[t * 3]; v.y = xf[t * 3 + 1]; v.z = xf[t * 3 + 2]; v.w = 0.f;
  xp[t] = v;
}

// ---------------- flow ----------------

// Packed 2-edge log-map accumulate: float2 lanes -> v_pk_* dual issue.
__device__ __forceinline__ void edge_accum_pk(
    vf2 p0, vf2 p1, vf2 p2, vf2 q0, vf2 q1, vf2 q2, vf2 w,
    vf2& a0, vf2& a1, vf2& a2) {
  vf2 cs = p0 * q0 + p1 * q1 + p2 * q2;
  cs = __builtin_elementwise_min(vf2{1.f, 1.f},
       __builtin_elementwise_max(vf2{-1.f, -1.f}, cs));
  vf2 u0 = q0 - cs * p0;
  vf2 u1 = q1 - cs * p1;
  vf2 u2 = q2 - cs * p2;
  vf2 un2 = __builtin_elementwise_max(u0 * u0 + u1 * u1 + u2 * u2,
                                      vf2{1e-24f, 1e-24f});
  vf2 ax = __builtin_elementwise_abs(cs);
  vf2 s = __builtin_elementwise_sqrt(vf2{1.f, 1.f} - ax);
  vf2 poly = ((ax * -0.0187293f + 0.0742610f) * ax - 0.2121144f) * ax
             + 1.5707288f;
  vf2 th = s * poly;
  vf2 theta;
  theta.x = (cs.x >= 0.0f) ? th.x : (PI_F - th.x);
  theta.y = (cs.y >= 0.0f) ? th.y : (PI_F - th.y);
  vf2 rsq;
  rsq.x = __builtin_amdgcn_rsqf(un2.x);
  rsq.y = __builtin_amdgcn_rsqf(un2.y);
  vf2 coef = w * theta * rsq;
  a0 += coef * u0;
  a1 += coef * u1;
  a2 += coef * u2;
}

__device__ __forceinline__ void node_step(
    float a0, float a1, float a2, float ws, float p0, float p1, float p2,
    float ts, float dsv, float& y0, float& y1, float& y2) {
  // v_lap = -agg/deg; nrm/scale sign-invariant; -(v_lap*scale)*t = +g*scale*t
  float invdg = __builtin_amdgcn_rcpf(ws + 1e-12f);
  float g0 = a0 * invdg, g1 = a1 * invdg, g2 = a2 * invdg;
  float nrm = sqrtf(fmaf(g0, g0, fmaf(g1, g1, g2 * g2)) + EPS64F);
  float tch = ts * ts * 0.5f;  // t_sqrt^2 / N_STEPS
  float dch = dsv * dsv;
  float alp = __builtin_amdgcn_rcpf(1.0f + __expf(dch - nrm));  // sigmoid
  float scale = (nrm * alp <= 1.0f) ? alp : __builtin_amdgcn_rcpf(nrm);
  float f = scale * tch;
  float v0 = g0 * f, v1 = g1 * f, v2 = g2 * f;
  float nv = sqrtf(fmaf(v0, v0, fmaf(v1, v1, v2 * v2)));
  float cn = __cosf(nv);
  float sc = (nv > 1e-20f) ? (__sinf(nv) * __builtin_amdgcn_rcpf(nv)) : 1.0f;
  float t0 = fmaf(cn, p0, sc * v0);
  float t1 = fmaf(cn, p1, sc * v1);
  float t2 = fmaf(cn, p2, sc * v2);
  float inv = __builtin_amdgcn_rsqf(fmaf(t0, t0, fmaf(t1, t1, t2 * t2)));
  y0 = t0 * inv; y1 = t1 * inv; y2 = t2 * inv;
}

// Padded-gather flow: q = one dwordx4 per edge-channel. pair holds (w, r*16).
// out48 != null => write unpadded final output, else padded yp.
__global__ __launch_bounds__(256, 8) void flow4_kernel(
    const vf4* __restrict__ xp, const int* __restrict__ row_start,
    const long long* __restrict__ pair, const float* __restrict__ tsq,
    const float* __restrict__ dsq, vf4* __restrict__ yp,
    float* __restrict__ out48, int N) {
  int node = blockIdx.x * 4 + (threadIdx.x >> 6);
  if (node >= N) return;
  int lane = threadIdx.x & 63;
  int c = lane & 15;
  int k = lane >> 4;
  int beg = row_start[node];
  int end = row_start[node + 1];
  vf4 p = xp[node * 16 + c];
  vf2 p0 = {p.x, p.x}, p1 = {p.y, p.y}, p2 = {p.z, p.z};
  vf2 a0 = {0.f, 0.f}, a1 = {0.f, 0.f}, a2 = {0.f, 0.f}, wsv = {0.f, 0.f};
  int iters = (end - beg + 15) >> 4;
  int j = beg + k;
  for (int t = 0; t < iters; ++t, j += 16) {
    long long e0 = __builtin_nontemporal_load(&pair[j]);
    long long e1 = __builtin_nontemporal_load(&pair[j + 4]);
    long long e2 = __builtin_nontemporal_load(&pair[j + 8]);
    long long e3 = __builtin_nontemporal_load(&pair[j + 12]);
    float w0 = (j      < end) ? __int_as_float((int)(e0 >> 32)) : 0.f;
    float w1 = (j + 4  < end) ? __int_as_float((int)(e1 >> 32)) : 0.f;
    float w2 = (j + 8  < end) ? __int_as_float((int)(e2 >> 32)) : 0.f;
    float w3 = (j + 12 < end) ? __int_as_float((int)(e3 >> 32)) : 0.f;
    vf4 qa = xp[(int)e0 + c];
    vf4 qb = xp[(int)e1 + c];
    vf4 qc = xp[(int)e2 + c];
    vf4 qd = xp[(int)e3 + c];
    vf2 wA = {w0, w1}, wB = {w2, w3};
    edge_accum_pk(p0, p1, p2, vf2{qa.x, qb.x}, vf2{qa.y, qb.y},
                  vf2{qa.z, qb.z}, wA, a0, a1, a2);
    edge_accum_pk(p0, p1, p2, vf2{qc.x, qd.x}, vf2{qc.y, qd.y},
                  vf2{qc.z, qd.z}, wB, a0, a1, a2);
    wsv += wA + wB;
  }
  float A0 = a0.x + a0.y, A1 = a1.x + a1.y, A2 = a2.x + a2.y;
  float ws = wsv.x + wsv.y;
  A0 += __shfl_xor(A0, 16); A1 += __shfl_xor(A1, 16);
  A2 += __shfl_xor(A2, 16); ws += __shfl_xor(ws, 16);
  A0 += __shfl_xor(A0, 32); A1 += __shfl_xor(A1, 32);
  A2 += __shfl_xor(A2, 32); ws += __shfl_xor(ws, 32);
  if (k == 0) {
    float y0, y1, y2;
    node_step(A0, A1, A2, ws, p.x, p.y, p.z, tsq[c], dsq[c], y0, y1, y2);
    if (out48) {
      int ip = node * 48 + c * 3;
      out48[ip] = y0; out48[ip + 1] = y1; out48[ip + 2] = y2;
    } else {
      vf4 v; v.x = y0; v.y = y1; v.z = y2; v.w = 0.f;
      yp[node * 16 + c] = v;
    }
  }
}

// Fallback step-1 flow (small ws): unpadded [N][48] gather (3 loads),
// padded output. row offset = (r*16)*3 = r*48.
__global__ __launch_bounds__(256) void flow3_kernel(
    const float* __restrict__ x48, const int* __restrict__ row_start,
    const long long* __restrict__ pair, const float* __restrict__ tsq,
    const float* __restrict__ dsq, vf4* __restrict__ yp, int N) {
  int node = blockIdx.x * 4 + (threadIdx.x >> 6);
  if (node >= N) return;
  int lane = threadIdx.x & 63;
  int c = lane & 15;
  int k = lane >> 4;
  int c3 = c * 3;
  int beg = row_start[node];
  int end = row_start[node + 1];
  int ip = node * 48 + c3;
  float ps0 = x48[ip], ps1 = x48[ip + 1], ps2 = x48[ip + 2];
  vf2 p0 = {ps0, ps0}, p1 = {ps1, ps1}, p2 = {ps2, ps2};
  vf2 a0 = {0.f, 0.f}, a1 = {0.f, 0.f}, a2 = {0.f, 0.f}, wsv = {0.f, 0.f};
  int iters = (end - beg + 15) >> 4;
  int j = beg + k;
  for (int t = 0; t < iters; ++t, j += 16) {
    long long e0 = __builtin_nontemporal_load(&pair[j]);
    long long e1 = __builtin_nontemporal_load(&pair[j + 4]);
    long long e2 = __builtin_nontemporal_load(&pair[j + 8]);
    long long e3 = __builtin_nontemporal_load(&pair[j + 12]);
    float w0 = (j      < end) ? __int_as_float((int)(e0 >> 32)) : 0.f;
    float w1 = (j + 4  < end) ? __int_as_float((int)(e1 >> 32)) : 0.f;
    float w2 = (j + 8  < end) ? __int_as_float((int)(e2 >> 32)) : 0.f;
    float w3 = (j + 12 < end) ? __int_as_float((int)(e3 >> 32)) : 0.f;
    const float* q0p = x48 + ((int)e0 * 3 + c3);
    const float* q1p = x48 + ((int)e1 * 3 + c3);
    const float* q2p = x48 + ((int)e2 * 3 + c3);
    const float* q3p = x48 + ((int)e3 * 3 + c3);
    float qa0 = q0p[0], qa1 = q0p[1], qa2 = q0p[2];
    float qb0 = q1p[0], qb1 = q1p[1], qb2 = q1p[2];
    float qc0 = q2p[0], qc1 = q2p[1], qc2 = q2p[2];
    float qd0 = q3p[0], qd1 = q3p[1], qd2 = q3p[2];
    vf2 wA = {w0, w1}, wB = {w2, w3};
    edge_accum_pk(p0, p1, p2, vf2{qa0, qb0}, vf2{qa1, qb1}, vf2{qa2, qb2},
                  wA, a0, a1, a2);
    edge_accum_pk(p0, p1, p2, vf2{qc0, qd0}, vf2{qc1, qd1}, vf2{qc2, qd2},
                  wB, a0, a1, a2);
    wsv += wA + wB;
  }
  float A0 = a0.x + a0.y, A1 = a1.x + a1.y, A2 = a2.x + a2.y;
  float ws = wsv.x + wsv.y;
  A0 += __shfl_xor(A0, 16); A1 += __shfl_xor(A1, 16);
  A2 += __shfl_xor(A2, 16); ws += __shfl_xor(ws, 16);
  A0 += __shfl_xor(A0, 32); A1 += __shfl_xor(A1, 32);
  A2 += __shfl_xor(A2, 32); ws += __shfl_xor(ws, 32);
  if (k == 0) {
    float y0, y1, y2;
    node_step(A0, A1, A2, ws, ps0, ps1, ps2, tsq[c], dsq[c], y0, y1, y2);
    vf4 v; v.x = y0; v.y = y1; v.z = y2; v.w = 0.f;
    yp[node * 16 + c] = v;
  }
}

static inline size_t al16(size_t x) { return (x + 15) & ~(size_t)15; }

extern "C" void kernel_launch(void* const* d_in, const int* in_sizes, int n_in,
                              void* d_out, int out_size, void* d_ws, size_t ws_size,
                              hipStream_t stream) {
  const float* nodes = (const float*)d_in[0];  // [N,16,3]
  const float* ew    = (const float*)d_in[1];  // [E]
  const float* tsq   = (const float*)d_in[2];  // [16]
  const float* dsq   = (const float*)d_in[3];  // [16]
  const int*   snd   = (const int*)d_in[4];    // [E]
  const int*   rcv   = (const int*)d_in[5];    // [E]
  float* out = (float*)d_out;

  int E = in_sizes[1];
  int N = in_sizes[0] / 48;

  size_t repB  = al16((size_t)NREP * N * 4);
  size_t rsB   = al16((size_t)(N + 4) * 4);
  size_t auxB  = 512;
  size_t pairB = al16((size_t)(E + 16) * 8);
  size_t xpB   = al16((size_t)N * 16 * 16);  // [N*16] float4
  size_t posB  = al16((size_t)E * 4);
  size_t zB    = (posB > xpB) ? posB : xpB;  // pos | xpB union
  size_t need_main = repB + rsB + auxB + pairB + xpB + zB;

  char* base = (char*)d_ws;
  int*       rep       = (int*)base;
  int*       row_start = (int*)(base + repB);
  int*       btot      = (int*)(base + repB + rsB);
  int*       boff      = btot + 64;
  long long* pair      = (long long*)(base + repB + rsB + auxB);
  char*      after     = base + repB + rsB + auxB + pairB;

  bool mainp = (ws_size >= need_main);
  vf4* xpA = (vf4*)after;                         // main only
  char* zreg = mainp ? (after + xpB) : after;     // pos | xpB(intermediate)
  int* pos = (int*)zreg;
  vf4* xpB_ = (vf4*)zreg;

  hipMemsetAsync(rep, 0, repB, stream);

  int E4 = E >> 2;
  int hb  = (E4 + 1023) / 1024;
  int fbk = (E4 + 511) / 512;
  int nb  = (N + 1023) / 1024;
  int cb  = (N * 16 + 255) / 256;
  int nfb = (N + 3) / 4;

  if (mainp) conv_kernel<<<cb, 256, 0, stream>>>(nodes, xpA, N * 16);
  hist_kernel<<<hb, 256, 0, stream>>>((const vi4*)snd, rep, (vi4*)pos,
                                      snd, pos, N, E);
  scanA_kernel<<<nb, 1024, 0, stream>>>(rep, row_start, btot, N);
  scanB_kernel<<<1, 64, 0, stream>>>(btot, boff, row_start, nb, N);
  scanC_kernel<<<nb, 1024, 0, stream>>>(row_start, boff, rep, N);
  fill_kernel<<<fbk, 256, 0, stream>>>((const vi4*)snd, (const vi4*)rcv,
                                       (const vf4*)ew, (const vi4*)pos,
                                       rep, pair, snd, rcv, ew, pos, N, E);

  if (mainp) {
    // step1: xpA -> xpB_ (padded); step2: xpB_ -> out (unpadded write)
    flow4_kernel<<<nfb, 256, 0, stream>>>(xpA, row_start, pair, tsq, dsq,
                                          xpB_, (float*)0, N);
    flow4_kernel<<<nfb, 256, 0, stream>>>(xpB_, row_start, pair, tsq, dsq,
                                          (vf4*)0, out, N);
  } else {
    // step1: unpadded gather nodes -> xpB_ ; step2: padded -> out
    flow3_kernel<<<nfb, 256, 0, stream>>>(nodes, row_start, pair, tsq, dsq,
                                          xpB_, N);
    flow4_kernel<<<nfb, 256, 0, stream>>>(xpB_, row_start, pair, tsq, dsq,
                                          (vf4*)0, out, N);
  }
}

// Round 12
// 298.420 us; speedup vs baseline: 1.1415x; 1.1415x over previous
//
#include <hip/hip_runtime.h>
#include <math.h>

// FlowLayer: 2 steps of manifold (S^2) graph heat flow.
// N=50000 nodes, C=16 channels, D=3, E=1.6M edges.
//
// Build (NO global atomics — R7/R10 showed device-scope atomicAdd walls at
// ~25G RMW/s): LDS-privatized histogram. Grid = (NC edge-chunks x NS
// node-subranges of 16K); block (c,s) counts chunk c's senders in subrange s
// via LDS atomicAdd (return value = slot within (node,chunk), fits a byte),
// dumps 16K counts to partial2. scan1: per-node exclusive prefix over chunks
// -> boff[c][v] + node totals; scanA/B/C: tile scan -> row_start; scanD:
// boff += row_start; fill: slot = boff[e>>15][snd] + pos[e], atomic-free.
//
// Flow: best measured variant (R10): wave per node, lane=(k*16+c), 16
// edges/wave-iter = 4 slots x 2 packed float2 pairs, unpadded [N][48] rows
// (192B = 3 cache lines), pair packs (w, rcv*48).
//
// NOTE: |u|^2 MUST be computed from u's components (not 1-cs^2): near
// antipodal pairs 1-cs^2 cancels catastrophically -> rsq explodes (R5 bug).

constexpr float EPS64F = 2.2204460492503131e-16f;  // np.float64 eps
constexpr float PI_F   = 3.14159265358979323846f;
constexpr int   SR_BITS = 14;                 // 16384-node subranges (64KB LDS)
constexpr int   CH_BITS = 15;                 // 32768-edge chunks

typedef int   vi4 __attribute__((ext_vector_type(4)));
typedef float vf4 __attribute__((ext_vector_type(4)));
typedef float vf2 __attribute__((ext_vector_type(2)));

// ---------------- CSR build ----------------

// LDS histogram: block (c = blockIdx.x, s = blockIdx.y).
__global__ __launch_bounds__(256) void lhist_kernel(
    const int* __restrict__ snd, unsigned char* __restrict__ pos,
    int* __restrict__ partial2, int E, int NC) {
  __shared__ int h[1 << SR_BITS];
  int tid = threadIdx.x;
  int c = blockIdx.x, s = blockIdx.y;
  for (int i = tid; i < (1 << SR_BITS); i += 256) h[i] = 0;
  __syncthreads();
  int base = c << CH_BITS;
  int cnt = min(1 << CH_BITS, E - base);
  int s0 = s << SR_BITS;
  const vi4* snd4 = (const vi4*)(snd + base);  // base is 32768-aligned
  int cnt4 = cnt >> 2;
  for (int i = tid; i < cnt4; i += 256) {
    vi4 sv = snd4[i];
    int e = base + (i << 2);
    int v;
    v = sv.x - s0; if ((unsigned)v < (1u << SR_BITS)) pos[e]     = (unsigned char)atomicAdd(&h[v], 1);
    v = sv.y - s0; if ((unsigned)v < (1u << SR_BITS)) pos[e + 1] = (unsigned char)atomicAdd(&h[v], 1);
    v = sv.z - s0; if ((unsigned)v < (1u << SR_BITS)) pos[e + 2] = (unsigned char)atomicAdd(&h[v], 1);
    v = sv.w - s0; if ((unsigned)v < (1u << SR_BITS)) pos[e + 3] = (unsigned char)atomicAdd(&h[v], 1);
  }
  if (tid == 0) {  // chunk tail (cnt % 4)
    for (int i = cnt4 << 2; i < cnt; ++i) {
      int v = snd[base + i] - s0;
      if ((unsigned)v < (1u << SR_BITS))
        pos[base + i] = (unsigned char)atomicAdd(&h[v], 1);
    }
  }
  __syncthreads();
  int* dst = partial2 + ((size_t)(s * NC + c) << SR_BITS);
  for (int i = tid; i < (1 << SR_BITS); i += 256) dst[i] = h[i];
}

// Per-node exclusive prefix over chunks; writes boff[c*N+v] and tot[v].
__global__ __launch_bounds__(256) void scan1_kernel(
    const int* __restrict__ partial2, int* __restrict__ boff,
    int* __restrict__ tot, int N, int NC) {
  int v = blockIdx.x * 256 + threadIdx.x;
  if (v >= N) return;
  int s = v >> SR_BITS, lv = v & ((1 << SR_BITS) - 1);
  int run = 0;
  for (int c = 0; c < NC; ++c) {
    int t = partial2[((size_t)(s * NC + c) << SR_BITS) + lv];
    boff[(size_t)c * N + v] = run;
    run += t;
  }
  tot[v] = run;
}

// Tile scan of tot -> tile-local exclusive row_start + per-tile totals.
__global__ __launch_bounds__(1024) void scanA_kernel(
    const int* __restrict__ tot, int* __restrict__ row_start,
    int* __restrict__ btot, int N) {
  __shared__ int wsum[16];
  int tid = threadIdx.x;
  int lane = tid & 63, wave = tid >> 6;
  int i = blockIdx.x * 1024 + tid;
  int v = (i < N) ? tot[i] : 0;
  int incl = v;
  #pragma unroll
  for (int off = 1; off < 64; off <<= 1) {
    int t = __shfl_up(incl, off, 64);
    if (lane >= off) incl += t;
  }
  if (lane == 63) wsum[wave] = incl;
  __syncthreads();
  if (wave == 0 && lane < 16) {
    int wincl = wsum[lane];
    #pragma unroll
    for (int off = 1; off < 16; off <<= 1) {
      int t = __shfl_up(wincl, off, 64);
      if (lane >= off) wincl += t;
    }
    wsum[lane] = wincl;
  }
  __syncthreads();
  int woff = (wave > 0) ? wsum[wave - 1] : 0;
  if (i < N) row_start[i] = woff + incl - v;
  if (tid == 0) btot[blockIdx.x] = wsum[15];
}

__global__ __launch_bounds__(64) void scanB_kernel(
    const int* __restrict__ btot, int* __restrict__ boffb,
    int* __restrict__ row_start, int nb, int N) {
  int lane = threadIdx.x;
  int v = (lane < nb) ? btot[lane] : 0;
  int incl = v;
  #pragma unroll
  for (int off = 1; off < 64; off <<= 1) {
    int t = __shfl_up(incl, off, 64);
    if (lane >= off) incl += t;
  }
  if (lane < nb) boffb[lane] = incl - v;
  if (lane == 63) row_start[N] = incl;  // grand total
}

__global__ __launch_bounds__(1024) void scanC_kernel(
    int* __restrict__ row_start, const int* __restrict__ boffb, int N) {
  int i = blockIdx.x * 1024 + threadIdx.x;
  if (i < N) row_start[i] += boffb[blockIdx.x];
}

// boff[c][v] += row_start[v]  (all coalesced)
__global__ __launch_bounds__(256) void scanD_kernel(
    int* __restrict__ boff, const int* __restrict__ row_start, int N, int NC) {
  int v = blockIdx.x * 256 + threadIdx.x;
  if (v >= N) return;
  int rs = row_start[v];
  for (int c = 0; c < NC; ++c) boff[(size_t)c * N + v] += rs;
}

// Atomic-free fill: slot = boff[chunk][snd] + pos[e]; packs (w, rcv*48);
// 16 zero sentinels past pair[E].
__global__ __launch_bounds__(256) void fill_kernel(
    const vi4* __restrict__ snd4, const vi4* __restrict__ rcv4,
    const vf4* __restrict__ ew4, const unsigned char* __restrict__ pos,
    const int* __restrict__ boff, long long* __restrict__ pair,
    const int* __restrict__ snd, const int* __restrict__ rcv,
    const float* __restrict__ ew, int N, int E) {
  int tid = threadIdx.x;
  int E4 = E >> 2;
  #pragma unroll
  for (int gg = 0; gg < 2; ++gg) {
    int g = blockIdx.x * 512 + gg * 256 + tid;
    if (g < E4) {
      int e = g << 2;
      const int* bc = boff + (size_t)(e >> CH_BITS) * N;  // same chunk for e..e+3
      vi4 s = __builtin_nontemporal_load(&snd4[g]);
      vi4 r = __builtin_nontemporal_load(&rcv4[g]);
      vf4 w = __builtin_nontemporal_load(&ew4[g]);
      unsigned pb = *(const unsigned*)(pos + e);
      pair[bc[s.x] + (pb & 255u)] =
          (long long)(((unsigned long long)(unsigned)__float_as_int(w.x) << 32) | (unsigned)(r.x * 48));
      pair[bc[s.y] + ((pb >> 8) & 255u)] =
          (long long)(((unsigned long long)(unsigned)__float_as_int(w.y) << 32) | (unsigned)(r.y * 48));
      pair[bc[s.z] + ((pb >> 16) & 255u)] =
          (long long)(((unsigned long long)(unsigned)__float_as_int(w.z) << 32) | (unsigned)(r.z * 48));
      pair[bc[s.w] + (pb >> 24)] =
          (long long)(((unsigned long long)(unsigned)__float_as_int(w.w) << 32) | (unsigned)(r.w * 48));
    }
  }
  if (blockIdx.x == 0 && tid == 0) {
    for (int e = E4 << 2; e < E; ++e) {  // edge tail
      pair[boff[(size_t)(e >> CH_BITS) * N + snd[e]] + pos[e]] =
          (long long)(((unsigned long long)(unsigned)__float_as_int(ew[e]) << 32) | (unsigned)(rcv[e] * 48));
    }
    for (int z = 0; z < 16; ++z) pair[(size_t)E + z] = 0;  // sentinels (w=0)
  }
}

// ---------------- flow (R10 flowp, best measured) ----------------

__device__ __forceinline__ void edge_accum_pk(
    vf2 p0, vf2 p1, vf2 p2, vf2 q0, vf2 q1, vf2 q2, vf2 w,
    vf2& a0, vf2& a1, vf2& a2) {
  vf2 cs = p0 * q0 + p1 * q1 + p2 * q2;
  cs = __builtin_elementwise_min(vf2{1.f, 1.f},
       __builtin_elementwise_max(vf2{-1.f, -1.f}, cs));
  vf2 u0 = q0 - cs * p0;
  vf2 u1 = q1 - cs * p1;
  vf2 u2 = q2 - cs * p2;
  vf2 un2 = __builtin_elementwise_max(u0 * u0 + u1 * u1 + u2 * u2,
                                      vf2{1e-24f, 1e-24f});
  vf2 ax = __builtin_elementwise_abs(cs);
  vf2 s = __builtin_elementwise_sqrt(vf2{1.f, 1.f} - ax);
  vf2 poly = ((ax * -0.0187293f + 0.0742610f) * ax - 0.2121144f) * ax
             + 1.5707288f;
  vf2 th = s * poly;
  vf2 theta;
  theta.x = (cs.x >= 0.0f) ? th.x : (PI_F - th.x);
  theta.y = (cs.y >= 0.0f) ? th.y : (PI_F - th.y);
  vf2 rsq;
  rsq.x = __builtin_amdgcn_rsqf(un2.x);
  rsq.y = __builtin_amdgcn_rsqf(un2.y);
  vf2 coef = w * theta * rsq;
  a0 += coef * u0;
  a1 += coef * u1;
  a2 += coef * u2;
}

__device__ __forceinline__ void node_step(
    float a0, float a1, float a2, float ws, float p0, float p1, float p2,
    float ts, float dsv, float& y0, float& y1, float& y2) {
  // v_lap = -agg/deg; nrm/scale sign-invariant; -(v_lap*scale)*t = +g*scale*t
  float invdg = __builtin_amdgcn_rcpf(ws + 1e-12f);
  float g0 = a0 * invdg, g1 = a1 * invdg, g2 = a2 * invdg;
  float nrm = sqrtf(fmaf(g0, g0, fmaf(g1, g1, g2 * g2)) + EPS64F);
  float tch = ts * ts * 0.5f;  // t_sqrt^2 / N_STEPS
  float dch = dsv * dsv;
  float alp = __builtin_amdgcn_rcpf(1.0f + __expf(dch - nrm));  // sigmoid
  float scale = (nrm * alp <= 1.0f) ? alp : __builtin_amdgcn_rcpf(nrm);
  float f = scale * tch;
  float v0 = g0 * f, v1 = g1 * f, v2 = g2 * f;
  float nv = sqrtf(fmaf(v0, v0, fmaf(v1, v1, v2 * v2)));
  float cn = __cosf(nv);
  float sc = (nv > 1e-20f) ? (__sinf(nv) * __builtin_amdgcn_rcpf(nv)) : 1.0f;
  float t0 = fmaf(cn, p0, sc * v0);
  float t1 = fmaf(cn, p1, sc * v1);
  float t2 = fmaf(cn, p2, sc * v2);
  float inv = __builtin_amdgcn_rsqf(fmaf(t0, t0, fmaf(t1, t1, t2 * t2)));
  y0 = t0 * inv; y1 = t1 * inv; y2 = t2 * inv;
}

__global__ __launch_bounds__(256) void flowp_kernel(
    const float* __restrict__ xin, const int* __restrict__ row_start,
    const long long* __restrict__ pair, const float* __restrict__ tsq,
    const float* __restrict__ dsq, float* __restrict__ xout, int N) {
  int node = blockIdx.x * 4 + (threadIdx.x >> 6);
  if (node >= N) return;
  int lane = threadIdx.x & 63;
  int c = lane & 15;
  int k = lane >> 4;
  int c3 = c * 3;
  int beg = row_start[node];
  int end = row_start[node + 1];
  int ip = node * 48 + c3;
  float ps0 = xin[ip], ps1 = xin[ip + 1], ps2 = xin[ip + 2];
  vf2 p0 = {ps0, ps0}, p1 = {ps1, ps1}, p2 = {ps2, ps2};
  vf2 a0 = {0.f, 0.f}, a1 = {0.f, 0.f}, a2 = {0.f, 0.f}, wsv = {0.f, 0.f};
  int iters = (end - beg + 15) >> 4;
  int j = beg + k;
  for (int t = 0; t < iters; ++t, j += 16) {
    long long e0 = __builtin_nontemporal_load(&pair[j]);
    long long e1 = __builtin_nontemporal_load(&pair[j + 4]);
    long long e2 = __builtin_nontemporal_load(&pair[j + 8]);
    long long e3 = __builtin_nontemporal_load(&pair[j + 12]);
    float w0 = (j      < end) ? __int_as_float((int)(e0 >> 32)) : 0.f;
    float w1 = (j + 4  < end) ? __int_as_float((int)(e1 >> 32)) : 0.f;
    float w2 = (j + 8  < end) ? __int_as_float((int)(e2 >> 32)) : 0.f;
    float w3 = (j + 12 < end) ? __int_as_float((int)(e3 >> 32)) : 0.f;
    const float* q0p = xin + ((int)e0 + c3);
    const float* q1p = xin + ((int)e1 + c3);
    const float* q2p = xin + ((int)e2 + c3);
    const float* q3p = xin + ((int)e3 + c3);
    float qa0 = q0p[0], qa1 = q0p[1], qa2 = q0p[2];
    float qb0 = q1p[0], qb1 = q1p[1], qb2 = q1p[2];
    float qc0 = q2p[0], qc1 = q2p[1], qc2 = q2p[2];
    float qd0 = q3p[0], qd1 = q3p[1], qd2 = q3p[2];
    vf2 wA = {w0, w1}, wB = {w2, w3};
    edge_accum_pk(p0, p1, p2, vf2{qa0, qb0}, vf2{qa1, qb1}, vf2{qa2, qb2},
                  wA, a0, a1, a2);
    edge_accum_pk(p0, p1, p2, vf2{qc0, qd0}, vf2{qc1, qd1}, vf2{qc2, qd2},
                  wB, a0, a1, a2);
    wsv += wA + wB;
  }
  float A0 = a0.x + a0.y, A1 = a1.x + a1.y, A2 = a2.x + a2.y;
  float ws = wsv.x + wsv.y;
  A0 += __shfl_xor(A0, 16); A1 += __shfl_xor(A1, 16);
  A2 += __shfl_xor(A2, 16); ws += __shfl_xor(ws, 16);
  A0 += __shfl_xor(A0, 32); A1 += __shfl_xor(A1, 32);
  A2 += __shfl_xor(A2, 32); ws += __shfl_xor(ws, 32);
  if (k == 0) {
    float y0, y1, y2;
    node_step(A0, A1, A2, ws, ps0, ps1, ps2, tsq[c], dsq[c], y0, y1, y2);
    xout[ip] = y0; xout[ip + 1] = y1; xout[ip + 2] = y2;
  }
}

static inline size_t al16(size_t x) { return (x + 15) & ~(size_t)15; }

extern "C" void kernel_launch(void* const* d_in, const int* in_sizes, int n_in,
                              void* d_out, int out_size, void* d_ws, size_t ws_size,
                              hipStream_t stream) {
  const float* nodes = (const float*)d_in[0];  // [N,16,3]
  const float* ew    = (const float*)d_in[1];  // [E]
  const float* tsq   = (const float*)d_in[2];  // [16]
  const float* dsq   = (const float*)d_in[3];  // [16]
  const int*   snd   = (const int*)d_in[4];    // [E]
  const int*   rcv   = (const int*)d_in[5];    // [E]
  float* out = (float*)d_out;

  int E = in_sizes[1];
  int N = in_sizes[0] / 48;

  int NS = (N + (1 << SR_BITS) - 1) >> SR_BITS;  // node subranges
  int NC = (E + (1 << CH_BITS) - 1) >> CH_BITS;  // edge chunks (<=64 for scanB? no: NC is chunk count for boff only)

  // workspace (~37.5MB @ N=50K,E=1.6M):
  // row_start[N+4] | aux(128) | pair[E+16] | partial2[NS*NC<<SR] | boff[NC*N]
  // | tot[N] | pos[E bytes]   ; xtmp (flow intermediate) aliases partial2.
  size_t rsB   = al16((size_t)(N + 4) * 4);
  size_t auxB  = 512;
  size_t pairB = al16((size_t)(E + 16) * 8);
  size_t p2B   = al16(((size_t)NS * NC << SR_BITS) * 4);
  size_t boffB = al16((size_t)NC * N * 4);
  size_t totB  = al16((size_t)N * 4);

  char* base = (char*)d_ws;
  int*           row_start = (int*)base;
  int*           btot      = (int*)(base + rsB);
  int*           boffb     = btot + 64;
  long long*     pair      = (long long*)(base + rsB + auxB);
  int*           partial2  = (int*)(base + rsB + auxB + pairB);
  int*           boff      = (int*)(base + rsB + auxB + pairB + p2B);
  int*           tot       = (int*)(base + rsB + auxB + pairB + p2B + boffB);
  unsigned char* pos       = (unsigned char*)(base + rsB + auxB + pairB + p2B + boffB + totB);
  float*         xtmp      = (float*)partial2;  // aliased; dead after scan1

  int E4  = E >> 2;
  int nb  = (N + 1023) / 1024;
  int nb2 = (N + 255) / 256;
  int fbk = (E4 + 511) / 512;
  int nfb = (N + 3) / 4;

  lhist_kernel<<<dim3(NC, NS), 256, 0, stream>>>(snd, pos, partial2, E, NC);
  scan1_kernel<<<nb2, 256, 0, stream>>>(partial2, boff, tot, N, NC);
  scanA_kernel<<<nb, 1024, 0, stream>>>(tot, row_start, btot, N);
  scanB_kernel<<<1, 64, 0, stream>>>(btot, boffb, row_start, nb, N);
  scanC_kernel<<<nb, 1024, 0, stream>>>(row_start, boffb, N);
  scanD_kernel<<<nb2, 256, 0, stream>>>(boff, row_start, N, NC);
  fill_kernel<<<fbk, 256, 0, stream>>>((const vi4*)snd, (const vi4*)rcv,
                                       (const vf4*)ew, pos, boff, pair,
                                       snd, rcv, ew, N, E);

  // step 1: nodes -> xtmp ; step 2: xtmp -> out (not in-place: reads neighbors)
  flowp_kernel<<<nfb, 256, 0, stream>>>(nodes, row_start, pair, tsq, dsq, xtmp, N);
  flowp_kernel<<<nfb, 256, 0, stream>>>(xtmp, row_start, pair, tsq, dsq, out, N);
}